// Round 3
// baseline (562.457 us; speedup 1.0000x reference)
//
#include <hip/hip_runtime.h>
#include <math.h>

// Problem constants (from reference)
#define BATCH 4
#define HW 512
#define NPLANE (512 * 512)
#define NS 12288      // oversampled points per batch
#define NU 3072       // top-k uncertain selected
#define NR 1024       // random extra points
#define NP 4096       // total selected points per batch
#define CF_CH 64
#define CC_CH 128
#define CIN 192
#define HID 256
#define OUTC 4
#define M_TOT (BATCH * NP)  // 16384
#define GCH_SPLIT 2         // point-chunks per (batch, channel) in gather

// ---------------------------------------------------------------------------
// Bit-exact replication of XLA:CPU's vectorized f32 expf (Cephes polynomial),
// strict per-op f32 rounding, no FMA. DO NOT TOUCH — top-k order depends on it.
// ---------------------------------------------------------------------------
__device__ __forceinline__ float xla_expf(float xin) {
  float x = fminf(fmaxf(xin, -88.3762626647949f), 88.3762626647950f);
  float fx = floorf(__fadd_rn(__fmul_rn(x, 1.44269504088896341f), 0.5f));
  float tmp = __fmul_rn(0.693359375f, fx);
  float z = __fmul_rn(-2.12194440e-4f, fx);
  x = __fsub_rn(__fsub_rn(x, tmp), z);
  float y = __fadd_rn(__fmul_rn(x, 1.9875691500E-4f), 1.3981999507E-3f);
  y = __fadd_rn(__fmul_rn(y, x), 8.3334519073E-3f);
  y = __fadd_rn(__fmul_rn(y, x), 4.1665795894E-2f);
  y = __fadd_rn(__fmul_rn(y, x), 1.6666665459E-1f);
  y = __fadd_rn(__fmul_rn(y, x), 5.0000001201E-1f);
  z = __fmul_rn(x, x);
  y = __fadd_rn(__fmul_rn(y, z), x);
  y = __fadd_rn(y, 1.0f);
  int n = (int)fx;
  float p2n = __int_as_float((n + 127) << 23);
  return __fmul_rn(y, p2n);
}

// ---------------------------------------------------------------------------
// K1: uncertainty at oversampled points — bit-replicates reference f32 chain.
// ---------------------------------------------------------------------------
__global__ void k_uncert(const float* __restrict__ logits,
                         const float* __restrict__ rp,
                         float* __restrict__ u) {
  int gid = blockIdx.x * 256 + threadIdx.x;
  if (gid >= BATCH * NS) return;
  int b = gid / NS;
  float px = rp[(size_t)gid * 2 + 0];
  float py = rp[(size_t)gid * 2 + 1];
  const float* plane = logits + (size_t)b * OUTC * NPLANE;  // channel 0

  float x = __fsub_rn(__fmul_rn(px, 512.0f), 0.5f);
  float y = __fsub_rn(__fmul_rn(py, 512.0f), 0.5f);
  float x0f = floorf(x), y0f = floorf(y);
  float wx = __fsub_rn(x, x0f);
  float wy = __fsub_rn(y, y0f);
  int x0 = (int)x0f, y0 = (int)y0f;
  int x1 = x0 + 1, y1 = y0 + 1;
  bool vx0 = (x0 >= 0) & (x0 < HW);
  bool vx1 = (x1 >= 0) & (x1 < HW);
  bool vy0 = (y0 >= 0) & (y0 < HW);
  bool vy1 = (y1 >= 0) & (y1 < HW);
  float g00 = (vx0 && vy0) ? plane[y0 * HW + x0] : 0.0f;
  float g10 = (vx1 && vy0) ? plane[y0 * HW + x1] : 0.0f;
  float g01 = (vx0 && vy1) ? plane[y1 * HW + x0] : 0.0f;
  float g11 = (vx1 && vy1) ? plane[y1 * HW + x1] : 0.0f;
  float omx = __fsub_rn(1.0f, wx);
  float omy = __fsub_rn(1.0f, wy);
  float w00 = __fmul_rn(omx, omy);
  float w10 = __fmul_rn(wx, omy);
  float w01 = __fmul_rn(omx, wy);
  float w11 = __fmul_rn(wx, wy);
  float s = __fadd_rn(
      __fadd_rn(__fadd_rn(__fmul_rn(g00, w00), __fmul_rn(g10, w10)),
                __fmul_rn(g01, w01)),
      __fmul_rn(g11, w11));
  float e = xla_expf(-s);
  float sig = __fdiv_rn(1.0f, __fadd_rn(1.0f, e));
  float t = __fmul_rn(fabsf(__fsub_rn(sig, 0.5f)), 2.0f);
  u[gid] = __fsub_rn(1.0f, t);
}

// ---------------------------------------------------------------------------
// K2: exact stable top-k via ranking (matches lax.top_k order).
// ---------------------------------------------------------------------------
__global__ __launch_bounds__(256) void k_select(const float* __restrict__ u,
                                                const float* __restrict__ rp,
                                                float* __restrict__ pts_out) {
  __shared__ __align__(16) float su[NS];
  int b = blockIdx.x / (NS / 256);
  int blk = blockIdx.x % (NS / 256);
  const float* ub = u + (size_t)b * NS;
  for (int t = threadIdx.x; t < NS / 4; t += 256)
    ((float4*)su)[t] = ((const float4*)ub)[t];
  __syncthreads();
  int i = blk * 256 + threadIdx.x;
  float ui = su[i];
  int rank = 0;
  for (int j = 0; j < NS; j += 4) {
    float4 v = *(const float4*)&su[j];
    rank += (v.x > ui) || (v.x == ui && (j + 0) < i);
    rank += (v.y > ui) || (v.y == ui && (j + 1) < i);
    rank += (v.z > ui) || (v.z == ui && (j + 2) < i);
    rank += (v.w > ui) || (v.w == ui && (j + 3) < i);
  }
  if (rank < NU) {
    pts_out[((size_t)b * NP + rank) * 2 + 0] = rp[((size_t)b * NS + i) * 2 + 0];
    pts_out[((size_t)b * NP + rank) * 2 + 1] = rp[((size_t)b * NS + i) * 2 + 1];
  }
}

// K2b: append the random-extra points.
__global__ void k_extra(const float* __restrict__ re, float* __restrict__ pts_out) {
  int gid = blockIdx.x * 256 + threadIdx.x;
  if (gid >= BATCH * NR) return;
  int b = gid / NR, j = gid % NR;
  pts_out[((size_t)b * NP + NU + j) * 2 + 0] = re[(size_t)gid * 2 + 0];
  pts_out[((size_t)b * NP + NU + j) * 2 + 1] = re[(size_t)gid * 2 + 1];
}

// ---------------------------------------------------------------------------
// K3a: per-point bilinear metadata: raw i00 (may be out-of-range; taps are
// predicated by vmask bits, never loaded when invalid), 4 weights.
// ---------------------------------------------------------------------------
__global__ void k_prep(const float* __restrict__ pts, int2* __restrict__ m2,
                       float4* __restrict__ wts) {
  int g = blockIdx.x * 256 + threadIdx.x;
  if (g >= M_TOT) return;
  float px = pts[(size_t)g * 2 + 0];
  float py = pts[(size_t)g * 2 + 1];
  float x = px * 512.0f - 0.5f;
  float y = py * 512.0f - 0.5f;
  float x0f = floorf(x), y0f = floorf(y);
  float wx = x - x0f, wy = y - y0f;
  int x0 = (int)x0f, y0 = (int)y0f;
  bool vx0 = (unsigned)x0 < (unsigned)HW;
  bool vx1 = (unsigned)(x0 + 1) < (unsigned)HW;
  bool vy0 = (unsigned)y0 < (unsigned)HW;
  bool vy1 = (unsigned)(y0 + 1) < (unsigned)HW;
  int vm = (int)(vx0 && vy0) | ((int)(vx1 && vy0) << 1) |
           ((int)(vx0 && vy1) << 2) | ((int)(vx1 && vy1) << 3);
  m2[g] = make_int2(y0 * HW + x0, vm);
  wts[g] = make_float4((1.0f - wx) * (1.0f - wy), wx * (1.0f - wy),
                       (1.0f - wx) * wy, wx * wy);
}

// ---------------------------------------------------------------------------
// K3b: counting-sort point indices by row (y0) per batch. Order within a
// bucket is nondeterministic but irrelevant (gather writes disjoint slots).
// ---------------------------------------------------------------------------
__global__ __launch_bounds__(512) void k_sort(const int2* __restrict__ m2,
                                              int* __restrict__ perm) {
  __shared__ int hist[512], pref[512];
  int b = blockIdx.x, tid = threadIdx.x;
  hist[tid] = 0;
  __syncthreads();
  for (int p = tid; p < NP; p += 512) {
    int i00 = m2[(size_t)b * NP + p].x;
    int key = min(max(i00, 0), NPLANE - 1) >> 9;  // y0 clamped to [0,511]
    atomicAdd(&hist[key], 1);
  }
  __syncthreads();
  int v = hist[tid];
  pref[tid] = v;
  __syncthreads();
  for (int d = 1; d < 512; d <<= 1) {
    int t = (tid >= d) ? pref[tid - d] : 0;
    __syncthreads();
    pref[tid] += t;
    __syncthreads();
  }
  hist[tid] = pref[tid] - v;  // exclusive prefix -> running offsets
  __syncthreads();
  for (int p = tid; p < NP; p += 512) {
    int i00 = m2[(size_t)b * NP + p].x;
    int key = min(max(i00, 0), NPLANE - 1) >> 9;
    int pos = atomicAdd(&hist[key], 1);
    perm[(size_t)b * NP + pos] = p;
  }
}

// ---------------------------------------------------------------------------
// K3c: locality-ordered gather. One block per (channel, batch, half); lanes
// walk row-sorted points so tap addresses coalesce into few lines and
// same-row reuse hits L1/L2. Output transposed: featsT[c][b*NP + p].
// ---------------------------------------------------------------------------
__global__ __launch_bounds__(256) void k_gather2(
    const float* __restrict__ fine, const float* __restrict__ coarse,
    const int* __restrict__ perm, const int2* __restrict__ m2,
    const float4* __restrict__ wts, float* __restrict__ featsT) {
  int c = blockIdx.x % CIN;
  int rem = blockIdx.x / CIN;
  int b = rem & (BATCH - 1);
  int half = rem >> 2;
  const float* plane = (c < CF_CH)
                           ? fine + ((size_t)b * CF_CH + c) * NPLANE
                           : coarse + ((size_t)b * CC_CH + (c - CF_CH)) * NPLANE;
  const int* permb = perm + (size_t)b * NP;
  const int2* m2b = m2 + (size_t)b * NP;
  const float4* wtsb = wts + (size_t)b * NP;
  float* outrow = featsT + (size_t)c * M_TOT + (size_t)b * NP;
  int s0 = half * (NP / GCH_SPLIT);
#pragma unroll 4
  for (int s = s0 + (int)threadIdx.x; s < s0 + NP / GCH_SPLIT; s += 256) {
    int p = permb[s];
    int2 mm = m2b[p];
    float4 w = wtsb[p];
    const float* bp = plane + mm.x;
    float r = 0.0f;
    if (mm.y & 1) r += bp[0] * w.x;
    if (mm.y & 2) r += bp[1] * w.y;
    if (mm.y & 4) r += bp[HW] * w.z;
    if (mm.y & 8) r += bp[HW + 1] * w.w;
    outrow[p] = r;
  }
}

// ---------------------------------------------------------------------------
// K4: GEMM layer 1 from transposed A (At[k][m]), C[M][256] row-major.
// 64x64 tile, BK=32, 256 threads, 4x4 acc. Inner loop identical to before.
// ---------------------------------------------------------------------------
__global__ __launch_bounds__(256) void k_gemm1_At(const float* __restrict__ At,
                                                  const float* __restrict__ W,
                                                  const float* __restrict__ bias,
                                                  float* __restrict__ C) {
  __shared__ __align__(16) float As[32][68];
  __shared__ __align__(16) float Bs[32][68];
  const int bx = blockIdx.x & 3;   // N tile
  const int by = blockIdx.x >> 2;  // M tile
  const int tid = threadIdx.x;
  const int tn = tid & 15, tm = tid >> 4;
  const int m_base = by * 64, n_base = bx * 64;
  float acc[4][4] = {};
  for (int k0 = 0; k0 < CIN; k0 += 32) {
#pragma unroll
    for (int r = 0; r < 2; ++r) {
      int t = tid + r * 256;
      int kk = t >> 4, mg = (t & 15) * 4;
      *(float4*)&As[kk][mg] =
          *(const float4*)&At[(size_t)(k0 + kk) * M_TOT + m_base + mg];
      int row = t >> 3, cg = (t & 7) * 4;
      float4 vw = *(const float4*)&W[(size_t)(n_base + row) * CIN + k0 + cg];
      Bs[cg + 0][row] = vw.x;
      Bs[cg + 1][row] = vw.y;
      Bs[cg + 2][row] = vw.z;
      Bs[cg + 3][row] = vw.w;
    }
    __syncthreads();
#pragma unroll
    for (int kk = 0; kk < 32; ++kk) {
      float4 a4 = *(const float4*)&As[kk][tm * 4];
      float4 b4 = *(const float4*)&Bs[kk][tn * 4];
      float av[4] = {a4.x, a4.y, a4.z, a4.w};
      float bw[4] = {b4.x, b4.y, b4.z, b4.w};
#pragma unroll
      for (int i = 0; i < 4; ++i)
#pragma unroll
        for (int j = 0; j < 4; ++j) acc[i][j] = fmaf(av[i], bw[j], acc[i][j]);
    }
    __syncthreads();
  }
  float bs[4];
#pragma unroll
  for (int j = 0; j < 4; ++j) bs[j] = bias[n_base + tn * 4 + j];
#pragma unroll
  for (int i = 0; i < 4; ++i) {
    float4 o;
    o.x = fmaxf(acc[i][0] + bs[0], 0.0f);
    o.y = fmaxf(acc[i][1] + bs[1], 0.0f);
    o.z = fmaxf(acc[i][2] + bs[2], 0.0f);
    o.w = fmaxf(acc[i][3] + bs[3], 0.0f);
    *(float4*)&C[(size_t)(m_base + tm * 4 + i) * HID + n_base + tn * 4] = o;
  }
}

// ---------------------------------------------------------------------------
// K5: GEMM layer 2 (row-major A), as before.
// ---------------------------------------------------------------------------
template <int K>
__global__ __launch_bounds__(256) void k_gemm_relu(const float* __restrict__ A,
                                                   const float* __restrict__ W,
                                                   const float* __restrict__ bias,
                                                   float* __restrict__ C) {
  __shared__ __align__(16) float As[32][68];
  __shared__ __align__(16) float Bs[32][68];
  const int bx = blockIdx.x & 3;
  const int by = blockIdx.x >> 2;
  const int tid = threadIdx.x;
  const int tn = tid & 15, tm = tid >> 4;
  const int m_base = by * 64, n_base = bx * 64;
  float acc[4][4] = {};
  for (int k0 = 0; k0 < K; k0 += 32) {
#pragma unroll
    for (int r = 0; r < 2; ++r) {
      int t = tid + r * 256;
      int row = t >> 3, cg = (t & 7) * 4;
      float4 va = *(const float4*)&A[(size_t)(m_base + row) * K + k0 + cg];
      As[cg + 0][row] = va.x;
      As[cg + 1][row] = va.y;
      As[cg + 2][row] = va.z;
      As[cg + 3][row] = va.w;
      float4 vw = *(const float4*)&W[(size_t)(n_base + row) * K + k0 + cg];
      Bs[cg + 0][row] = vw.x;
      Bs[cg + 1][row] = vw.y;
      Bs[cg + 2][row] = vw.z;
      Bs[cg + 3][row] = vw.w;
    }
    __syncthreads();
#pragma unroll
    for (int kk = 0; kk < 32; ++kk) {
      float4 a4 = *(const float4*)&As[kk][tm * 4];
      float4 b4 = *(const float4*)&Bs[kk][tn * 4];
      float av[4] = {a4.x, a4.y, a4.z, a4.w};
      float bw[4] = {b4.x, b4.y, b4.z, b4.w};
#pragma unroll
      for (int i = 0; i < 4; ++i)
#pragma unroll
        for (int j = 0; j < 4; ++j) acc[i][j] = fmaf(av[i], bw[j], acc[i][j]);
    }
    __syncthreads();
  }
  float bs[4];
#pragma unroll
  for (int j = 0; j < 4; ++j) bs[j] = bias[n_base + tn * 4 + j];
#pragma unroll
  for (int i = 0; i < 4; ++i) {
    float4 o;
    o.x = fmaxf(acc[i][0] + bs[0], 0.0f);
    o.y = fmaxf(acc[i][1] + bs[1], 0.0f);
    o.z = fmaxf(acc[i][2] + bs[2], 0.0f);
    o.w = fmaxf(acc[i][3] + bs[3], 0.0f);
    *(float4*)&C[(size_t)(m_base + tm * 4 + i) * HID + n_base + tn * 4] = o;
  }
}

// ---------------------------------------------------------------------------
// K6: final layer, 4 outputs per point, shuffle reduce.
// ---------------------------------------------------------------------------
__global__ __launch_bounds__(256) void k_out(const float* __restrict__ h,
                                             const float* __restrict__ W3,
                                             const float* __restrict__ b3,
                                             float* __restrict__ out) {
  int gp = blockIdx.x * 4 + (threadIdx.x >> 6);
  int lane = threadIdx.x & 63;
  const float* hr = h + (size_t)gp * HID;
  float4 hv = *(const float4*)&hr[lane * 4];
  float s[4];
#pragma unroll
  for (int o = 0; o < 4; ++o) {
    float4 w = *(const float4*)&W3[o * HID + lane * 4];
    s[o] = hv.x * w.x + hv.y * w.y + hv.z * w.z + hv.w * w.w;
  }
#pragma unroll
  for (int off = 32; off; off >>= 1)
#pragma unroll
    for (int o = 0; o < 4; ++o) s[o] += __shfl_xor(s[o], off, 64);
  if (lane == 0) {
    int b = gp / NP, n = gp % NP;
#pragma unroll
    for (int o = 0; o < 4; ++o)
      out[((size_t)b * OUTC + o) * NP + n] = s[o] + b3[o];
  }
}

extern "C" void kernel_launch(void* const* d_in, const int* in_sizes, int n_in,
                              void* d_out, int out_size, void* d_ws, size_t ws_size,
                              hipStream_t stream) {
  const float* fine = (const float*)d_in[0];
  const float* coarse = (const float*)d_in[1];
  const float* logits = (const float*)d_in[2];
  const float* rand_points = (const float*)d_in[3];
  const float* rand_extra = (const float*)d_in[4];
  const float* W1 = (const float*)d_in[5];
  const float* b1 = (const float*)d_in[6];
  const float* W2 = (const float*)d_in[7];
  const float* b2 = (const float*)d_in[8];
  const float* W3 = (const float*)d_in[9];
  const float* b3 = (const float*)d_in[10];
  float* out = (float*)d_out;

  float* out_logits = out;
  float* out_points = out + (size_t)BATCH * OUTC * NP;

  // ws layout (bytes): u | m2 | wts | perm | featsT | h1 | h2  (~45 MiB)
  char* ws = (char*)d_ws;
  float* u = (float*)(ws + 0);              // 196608
  int2* m2 = (int2*)(ws + 196608);          // 131072
  float4* wts = (float4*)(ws + 327680);     // 262144
  int* perm = (int*)(ws + 589824);          // 65536
  float* featsT = (float*)(ws + 655360);    // 12582912
  float* h1 = (float*)(ws + 13238272);      // 16777216
  float* h2 = (float*)(ws + 30015488);      // 16777216

  k_uncert<<<(BATCH * NS + 255) / 256, 256, 0, stream>>>(logits, rand_points, u);
  k_select<<<BATCH * (NS / 256), 256, 0, stream>>>(u, rand_points, out_points);
  k_extra<<<(BATCH * NR + 255) / 256, 256, 0, stream>>>(rand_extra, out_points);
  k_prep<<<(M_TOT + 255) / 256, 256, 0, stream>>>(out_points, m2, wts);
  k_sort<<<BATCH, 512, 0, stream>>>(m2, perm);
  k_gather2<<<CIN * BATCH * GCH_SPLIT, 256, 0, stream>>>(fine, coarse, perm, m2,
                                                         wts, featsT);
  k_gemm1_At<<<(M_TOT / 64) * 4, 256, 0, stream>>>(featsT, W1, b1, h1);
  k_gemm_relu<HID><<<(M_TOT / 64) * 4, 256, 0, stream>>>(h1, W2, b2, h2);
  k_out<<<M_TOT / 4, 256, 0, stream>>>(h2, W3, b3, out_logits);
}

// Round 5
// 531.987 us; speedup vs baseline: 1.0573x; 1.0573x over previous
//
#include <hip/hip_runtime.h>
#include <math.h>

// Problem constants (from reference)
#define BATCH 4
#define HW 512
#define NPLANE (512 * 512)
#define NS 12288      // oversampled points per batch
#define NU 3072       // top-k uncertain selected
#define NR 1024       // random extra points
#define NP 4096       // total selected points per batch
#define CF_CH 64
#define CC_CH 128
#define CIN 192
#define HID 256
#define OUTC 4
#define M_TOT (BATCH * NP)  // 16384
#define GCH_SPLIT 2         // point-chunks per (batch, channel) in gather

// ---------------------------------------------------------------------------
// Bit-exact replication of XLA:CPU's vectorized f32 expf (Cephes polynomial),
// strict per-op f32 rounding, no FMA. DO NOT TOUCH — top-k order depends on it.
// ---------------------------------------------------------------------------
__device__ __forceinline__ float xla_expf(float xin) {
  float x = fminf(fmaxf(xin, -88.3762626647949f), 88.3762626647950f);
  float fx = floorf(__fadd_rn(__fmul_rn(x, 1.44269504088896341f), 0.5f));
  float tmp = __fmul_rn(0.693359375f, fx);
  float z = __fmul_rn(-2.12194440e-4f, fx);
  x = __fsub_rn(__fsub_rn(x, tmp), z);
  float y = __fadd_rn(__fmul_rn(x, 1.9875691500E-4f), 1.3981999507E-3f);
  y = __fadd_rn(__fmul_rn(y, x), 8.3334519073E-3f);
  y = __fadd_rn(__fmul_rn(y, x), 4.1665795894E-2f);
  y = __fadd_rn(__fmul_rn(y, x), 1.6666665459E-1f);
  y = __fadd_rn(__fmul_rn(y, x), 5.0000001201E-1f);
  z = __fmul_rn(x, x);
  y = __fadd_rn(__fmul_rn(y, z), x);
  y = __fadd_rn(y, 1.0f);
  int n = (int)fx;
  float p2n = __int_as_float((n + 127) << 23);
  return __fmul_rn(y, p2n);
}

// ---------------------------------------------------------------------------
// K1: uncertainty at oversampled points — bit-replicates reference f32 chain.
// (R2-verified version: stores plain float u.)
// ---------------------------------------------------------------------------
__global__ void k_uncert(const float* __restrict__ logits,
                         const float* __restrict__ rp,
                         float* __restrict__ u) {
  int gid = blockIdx.x * 256 + threadIdx.x;
  if (gid >= BATCH * NS) return;
  int b = gid / NS;
  float px = rp[(size_t)gid * 2 + 0];
  float py = rp[(size_t)gid * 2 + 1];
  const float* plane = logits + (size_t)b * OUTC * NPLANE;  // channel 0

  float x = __fsub_rn(__fmul_rn(px, 512.0f), 0.5f);
  float y = __fsub_rn(__fmul_rn(py, 512.0f), 0.5f);
  float x0f = floorf(x), y0f = floorf(y);
  float wx = __fsub_rn(x, x0f);
  float wy = __fsub_rn(y, y0f);
  int x0 = (int)x0f, y0 = (int)y0f;
  int x1 = x0 + 1, y1 = y0 + 1;
  bool vx0 = (x0 >= 0) & (x0 < HW);
  bool vx1 = (x1 >= 0) & (x1 < HW);
  bool vy0 = (y0 >= 0) & (y0 < HW);
  bool vy1 = (y1 >= 0) & (y1 < HW);
  float g00 = (vx0 && vy0) ? plane[y0 * HW + x0] : 0.0f;
  float g10 = (vx1 && vy0) ? plane[y0 * HW + x1] : 0.0f;
  float g01 = (vx0 && vy1) ? plane[y1 * HW + x0] : 0.0f;
  float g11 = (vx1 && vy1) ? plane[y1 * HW + x1] : 0.0f;
  float omx = __fsub_rn(1.0f, wx);
  float omy = __fsub_rn(1.0f, wy);
  float w00 = __fmul_rn(omx, omy);
  float w10 = __fmul_rn(wx, omy);
  float w01 = __fmul_rn(omx, wy);
  float w11 = __fmul_rn(wx, wy);
  float s = __fadd_rn(
      __fadd_rn(__fadd_rn(__fmul_rn(g00, w00), __fmul_rn(g10, w10)),
                __fmul_rn(g01, w01)),
      __fmul_rn(g11, w11));
  float e = xla_expf(-s);
  float sig = __fdiv_rn(1.0f, __fadd_rn(1.0f, e));
  float t = __fmul_rn(fabsf(__fsub_rn(sig, 0.5f)), 2.0f);
  u[gid] = __fsub_rn(1.0f, t);
}

// ---------------------------------------------------------------------------
// K2: exact stable top-k via ranking (R2-verified). rank = #{j : u[j]>u[i] or
// (u[j]==u[i] and j<i)}; selected (rank<NU) point goes to slot `rank`.
// ---------------------------------------------------------------------------
__global__ __launch_bounds__(256) void k_select(const float* __restrict__ u,
                                                const float* __restrict__ rp,
                                                float* __restrict__ pts_out) {
  __shared__ __align__(16) float su[NS];
  int b = blockIdx.x / (NS / 256);
  int blk = blockIdx.x % (NS / 256);
  const float* ub = u + (size_t)b * NS;
  for (int t = threadIdx.x; t < NS / 4; t += 256)
    ((float4*)su)[t] = ((const float4*)ub)[t];
  __syncthreads();
  int i = blk * 256 + threadIdx.x;
  float ui = su[i];
  int rank = 0;
  for (int j = 0; j < NS; j += 4) {
    float4 v = *(const float4*)&su[j];
    rank += (v.x > ui) || (v.x == ui && (j + 0) < i);
    rank += (v.y > ui) || (v.y == ui && (j + 1) < i);
    rank += (v.z > ui) || (v.z == ui && (j + 2) < i);
    rank += (v.w > ui) || (v.w == ui && (j + 3) < i);
  }
  if (rank < NU) {
    pts_out[((size_t)b * NP + rank) * 2 + 0] = rp[((size_t)b * NS + i) * 2 + 0];
    pts_out[((size_t)b * NP + rank) * 2 + 1] = rp[((size_t)b * NS + i) * 2 + 1];
  }
}

// K2b: append the random-extra points (R2-verified).
__global__ void k_extra(const float* __restrict__ re, float* __restrict__ pts_out) {
  int gid = blockIdx.x * 256 + threadIdx.x;
  if (gid >= BATCH * NR) return;
  int b = gid / NR, j = gid % NR;
  pts_out[((size_t)b * NP + NU + j) * 2 + 0] = re[(size_t)gid * 2 + 0];
  pts_out[((size_t)b * NP + NU + j) * 2 + 1] = re[(size_t)gid * 2 + 1];
}

// ---------------------------------------------------------------------------
// K3a: per-point bilinear metadata: i00 (may be out-of-range; taps predicated
// by vmask bits, never loaded when invalid), 4 weights.
// ---------------------------------------------------------------------------
__global__ void k_prep(const float* __restrict__ pts, int2* __restrict__ m2,
                       float4* __restrict__ wts) {
  int g = blockIdx.x * 256 + threadIdx.x;
  if (g >= M_TOT) return;
  float px = pts[(size_t)g * 2 + 0];
  float py = pts[(size_t)g * 2 + 1];
  float x = px * 512.0f - 0.5f;
  float y = py * 512.0f - 0.5f;
  float x0f = floorf(x), y0f = floorf(y);
  float wx = x - x0f, wy = y - y0f;
  int x0 = (int)x0f, y0 = (int)y0f;
  bool vx0 = (unsigned)x0 < (unsigned)HW;
  bool vx1 = (unsigned)(x0 + 1) < (unsigned)HW;
  bool vy0 = (unsigned)y0 < (unsigned)HW;
  bool vy1 = (unsigned)(y0 + 1) < (unsigned)HW;
  int vm = (int)(vx0 && vy0) | ((int)(vx1 && vy0) << 1) |
           ((int)(vx0 && vy1) << 2) | ((int)(vx1 && vy1) << 3);
  m2[g] = make_int2(y0 * HW + x0, vm);
  wts[g] = make_float4((1.0f - wx) * (1.0f - wy), wx * (1.0f - wy),
                       (1.0f - wx) * wy, wx * wy);
}

// ---------------------------------------------------------------------------
// K3b: gather, natural point order, one block per (channel, batch, half).
// Coalesced metadata reads and featsT stores; scattered plane taps are the
// compulsory traffic. Output transposed: featsT[c][b*NP + s].
// ---------------------------------------------------------------------------
__global__ __launch_bounds__(256) void k_gather3(
    const float* __restrict__ fine, const float* __restrict__ coarse,
    const int2* __restrict__ m2, const float4* __restrict__ wts,
    float* __restrict__ featsT) {
  int c = blockIdx.x % CIN;
  int rem = blockIdx.x / CIN;
  int b = rem & (BATCH - 1);
  int half = rem >> 2;
  const float* plane = (c < CF_CH)
                           ? fine + ((size_t)b * CF_CH + c) * NPLANE
                           : coarse + ((size_t)b * CC_CH + (c - CF_CH)) * NPLANE;
  const int2* m2b = m2 + (size_t)b * NP;
  const float4* wtsb = wts + (size_t)b * NP;
  float* outrow = featsT + (size_t)c * M_TOT + (size_t)b * NP;
  int s0 = half * (NP / GCH_SPLIT);
#pragma unroll 4
  for (int s = s0 + (int)threadIdx.x; s < s0 + NP / GCH_SPLIT; s += 256) {
    int2 mm = m2b[s];
    float4 w = wtsb[s];
    const float* bp = plane + mm.x;
    float t00 = 0.0f, t10 = 0.0f, t01 = 0.0f, t11 = 0.0f;
    if (mm.y & 1) t00 = bp[0] * w.x;
    if (mm.y & 2) t10 = bp[1] * w.y;
    if (mm.y & 4) t01 = bp[HW] * w.z;
    if (mm.y & 8) t11 = bp[HW + 1] * w.w;
    outrow[s] = ((t00 + t10) + t01) + t11;
  }
}

// ---------------------------------------------------------------------------
// K4: GEMM layer 1 from transposed A (At[k][m]), C[M][256] row-major.
// 64x64 tile, BK=32, 256 threads, 4x4 acc.
// ---------------------------------------------------------------------------
__global__ __launch_bounds__(256) void k_gemm1_At(const float* __restrict__ At,
                                                  const float* __restrict__ W,
                                                  const float* __restrict__ bias,
                                                  float* __restrict__ C) {
  __shared__ __align__(16) float As[32][68];
  __shared__ __align__(16) float Bs[32][68];
  const int bx = blockIdx.x & 3;   // N tile
  const int by = blockIdx.x >> 2;  // M tile
  const int tid = threadIdx.x;
  const int tn = tid & 15, tm = tid >> 4;
  const int m_base = by * 64, n_base = bx * 64;
  float acc[4][4] = {};
  for (int k0 = 0; k0 < CIN; k0 += 32) {
#pragma unroll
    for (int r = 0; r < 2; ++r) {
      int t = tid + r * 256;
      int kk = t >> 4, mg = (t & 15) * 4;
      *(float4*)&As[kk][mg] =
          *(const float4*)&At[(size_t)(k0 + kk) * M_TOT + m_base + mg];
      int row = t >> 3, cg = (t & 7) * 4;
      float4 vw = *(const float4*)&W[(size_t)(n_base + row) * CIN + k0 + cg];
      Bs[cg + 0][row] = vw.x;
      Bs[cg + 1][row] = vw.y;
      Bs[cg + 2][row] = vw.z;
      Bs[cg + 3][row] = vw.w;
    }
    __syncthreads();
#pragma unroll
    for (int kk = 0; kk < 32; ++kk) {
      float4 a4 = *(const float4*)&As[kk][tm * 4];
      float4 b4 = *(const float4*)&Bs[kk][tn * 4];
      float av[4] = {a4.x, a4.y, a4.z, a4.w};
      float bw[4] = {b4.x, b4.y, b4.z, b4.w};
#pragma unroll
      for (int i = 0; i < 4; ++i)
#pragma unroll
        for (int j = 0; j < 4; ++j) acc[i][j] = fmaf(av[i], bw[j], acc[i][j]);
    }
    __syncthreads();
  }
  float bs[4];
#pragma unroll
  for (int j = 0; j < 4; ++j) bs[j] = bias[n_base + tn * 4 + j];
#pragma unroll
  for (int i = 0; i < 4; ++i) {
    float4 o;
    o.x = fmaxf(acc[i][0] + bs[0], 0.0f);
    o.y = fmaxf(acc[i][1] + bs[1], 0.0f);
    o.z = fmaxf(acc[i][2] + bs[2], 0.0f);
    o.w = fmaxf(acc[i][3] + bs[3], 0.0f);
    *(float4*)&C[(size_t)(m_base + tm * 4 + i) * HID + n_base + tn * 4] = o;
  }
}

// ---------------------------------------------------------------------------
// K5: GEMM layer 2 (row-major A).
// ---------------------------------------------------------------------------
template <int K>
__global__ __launch_bounds__(256) void k_gemm_relu(const float* __restrict__ A,
                                                   const float* __restrict__ W,
                                                   const float* __restrict__ bias,
                                                   float* __restrict__ C) {
  __shared__ __align__(16) float As[32][68];
  __shared__ __align__(16) float Bs[32][68];
  const int bx = blockIdx.x & 3;
  const int by = blockIdx.x >> 2;
  const int tid = threadIdx.x;
  const int tn = tid & 15, tm = tid >> 4;
  const int m_base = by * 64, n_base = bx * 64;
  float acc[4][4] = {};
  for (int k0 = 0; k0 < K; k0 += 32) {
#pragma unroll
    for (int r = 0; r < 2; ++r) {
      int t = tid + r * 256;
      int row = t >> 3, cg = (t & 7) * 4;
      float4 va = *(const float4*)&A[(size_t)(m_base + row) * K + k0 + cg];
      As[cg + 0][row] = va.x;
      As[cg + 1][row] = va.y;
      As[cg + 2][row] = va.z;
      As[cg + 3][row] = va.w;
      float4 vw = *(const float4*)&W[(size_t)(n_base + row) * K + k0 + cg];
      Bs[cg + 0][row] = vw.x;
      Bs[cg + 1][row] = vw.y;
      Bs[cg + 2][row] = vw.z;
      Bs[cg + 3][row] = vw.w;
    }
    __syncthreads();
#pragma unroll
    for (int kk = 0; kk < 32; ++kk) {
      float4 a4 = *(const float4*)&As[kk][tm * 4];
      float4 b4 = *(const float4*)&Bs[kk][tn * 4];
      float av[4] = {a4.x, a4.y, a4.z, a4.w};
      float bw[4] = {b4.x, b4.y, b4.z, b4.w};
#pragma unroll
      for (int i = 0; i < 4; ++i)
#pragma unroll
        for (int j = 0; j < 4; ++j) acc[i][j] = fmaf(av[i], bw[j], acc[i][j]);
    }
    __syncthreads();
  }
  float bs[4];
#pragma unroll
  for (int j = 0; j < 4; ++j) bs[j] = bias[n_base + tn * 4 + j];
#pragma unroll
  for (int i = 0; i < 4; ++i) {
    float4 o;
    o.x = fmaxf(acc[i][0] + bs[0], 0.0f);
    o.y = fmaxf(acc[i][1] + bs[1], 0.0f);
    o.z = fmaxf(acc[i][2] + bs[2], 0.0f);
    o.w = fmaxf(acc[i][3] + bs[3], 0.0f);
    *(float4*)&C[(size_t)(m_base + tm * 4 + i) * HID + n_base + tn * 4] = o;
  }
}

// ---------------------------------------------------------------------------
// K6: final layer, 4 outputs per point, shuffle reduce.
// ---------------------------------------------------------------------------
__global__ __launch_bounds__(256) void k_out(const float* __restrict__ h,
                                             const float* __restrict__ W3,
                                             const float* __restrict__ b3,
                                             float* __restrict__ out) {
  int gp = blockIdx.x * 4 + (threadIdx.x >> 6);
  int lane = threadIdx.x & 63;
  const float* hr = h + (size_t)gp * HID;
  float4 hv = *(const float4*)&hr[lane * 4];
  float s[4];
#pragma unroll
  for (int o = 0; o < 4; ++o) {
    float4 w = *(const float4*)&W3[o * HID + lane * 4];
    s[o] = hv.x * w.x + hv.y * w.y + hv.z * w.z + hv.w * w.w;
  }
#pragma unroll
  for (int off = 32; off; off >>= 1)
#pragma unroll
    for (int o = 0; o < 4; ++o) s[o] += __shfl_xor(s[o], off, 64);
  if (lane == 0) {
    int b = gp / NP, n = gp % NP;
#pragma unroll
    for (int o = 0; o < 4; ++o)
      out[((size_t)b * OUTC + o) * NP + n] = s[o] + b3[o];
  }
}

extern "C" void kernel_launch(void* const* d_in, const int* in_sizes, int n_in,
                              void* d_out, int out_size, void* d_ws, size_t ws_size,
                              hipStream_t stream) {
  const float* fine = (const float*)d_in[0];
  const float* coarse = (const float*)d_in[1];
  const float* logits = (const float*)d_in[2];
  const float* rand_points = (const float*)d_in[3];
  const float* rand_extra = (const float*)d_in[4];
  const float* W1 = (const float*)d_in[5];
  const float* b1 = (const float*)d_in[6];
  const float* W2 = (const float*)d_in[7];
  const float* b2 = (const float*)d_in[8];
  const float* W3 = (const float*)d_in[9];
  const float* b3 = (const float*)d_in[10];
  float* out = (float*)d_out;

  float* out_logits = out;
  float* out_points = out + (size_t)BATCH * OUTC * NP;

  // ws layout (bytes): u | m2 | wts | featsT | h1 | h2
  char* ws = (char*)d_ws;
  float* u = (float*)(ws + 0);              // 196608
  int2* m2 = (int2*)(ws + 196608);          // 131072
  float4* wts = (float4*)(ws + 327680);     // 262144
  float* featsT = (float*)(ws + 589824);    // 12582912
  float* h1 = (float*)(ws + 13172736);      // 16777216
  float* h2 = (float*)(ws + 29949952);      // 16777216

  k_uncert<<<(BATCH * NS + 255) / 256, 256, 0, stream>>>(logits, rand_points, u);
  k_select<<<BATCH * (NS / 256), 256, 0, stream>>>(u, rand_points, out_points);
  k_extra<<<(BATCH * NR + 255) / 256, 256, 0, stream>>>(rand_extra, out_points);
  k_prep<<<(M_TOT + 255) / 256, 256, 0, stream>>>(out_points, m2, wts);
  k_gather3<<<CIN * BATCH * GCH_SPLIT, 256, 0, stream>>>(fine, coarse, m2, wts,
                                                         featsT);
  k_gemm1_At<<<(M_TOT / 64) * 4, 256, 0, stream>>>(featsT, W1, b1, h1);
  k_gemm_relu<HID><<<(M_TOT / 64) * 4, 256, 0, stream>>>(h1, W2, b2, h2);
  k_out<<<M_TOT / 4, 256, 0, stream>>>(h2, W3, b3, out_logits);
}

// Round 6
// 326.400 us; speedup vs baseline: 1.7232x; 1.6299x over previous
//
#include <hip/hip_runtime.h>
#include <math.h>

// Problem constants (from reference)
#define BATCH 4
#define HW 512
#define NPLANE (512 * 512)
#define NS 12288      // oversampled points per batch
#define NU 3072       // top-k uncertain selected
#define NR 1024       // random extra points
#define NP 4096       // total selected points per batch
#define CF_CH 64
#define CC_CH 128
#define CIN 192
#define HID 256
#define OUTC 4
#define M_TOT (BATCH * NP)  // 16384
#define GCH_SPLIT 4         // point-chunks per (batch, channel) in gather

// ---------------------------------------------------------------------------
// Bit-exact replication of XLA:CPU's vectorized f32 expf (Cephes polynomial),
// strict per-op f32 rounding, no FMA. DO NOT TOUCH — top-k order depends on it.
// ---------------------------------------------------------------------------
__device__ __forceinline__ float xla_expf(float xin) {
  float x = fminf(fmaxf(xin, -88.3762626647949f), 88.3762626647950f);
  float fx = floorf(__fadd_rn(__fmul_rn(x, 1.44269504088896341f), 0.5f));
  float tmp = __fmul_rn(0.693359375f, fx);
  float z = __fmul_rn(-2.12194440e-4f, fx);
  x = __fsub_rn(__fsub_rn(x, tmp), z);
  float y = __fadd_rn(__fmul_rn(x, 1.9875691500E-4f), 1.3981999507E-3f);
  y = __fadd_rn(__fmul_rn(y, x), 8.3334519073E-3f);
  y = __fadd_rn(__fmul_rn(y, x), 4.1665795894E-2f);
  y = __fadd_rn(__fmul_rn(y, x), 1.6666665459E-1f);
  y = __fadd_rn(__fmul_rn(y, x), 5.0000001201E-1f);
  z = __fmul_rn(x, x);
  y = __fadd_rn(__fmul_rn(y, z), x);
  y = __fadd_rn(y, 1.0f);
  int n = (int)fx;
  float p2n = __int_as_float((n + 127) << 23);
  return __fmul_rn(y, p2n);
}

// ---------------------------------------------------------------------------
// K1: uncertainty at oversampled points — bit-replicates reference f32 chain.
// (R2-verified.)
// ---------------------------------------------------------------------------
__global__ void k_uncert(const float* __restrict__ logits,
                         const float* __restrict__ rp,
                         float* __restrict__ u) {
  int gid = blockIdx.x * 256 + threadIdx.x;
  if (gid >= BATCH * NS) return;
  int b = gid / NS;
  float px = rp[(size_t)gid * 2 + 0];
  float py = rp[(size_t)gid * 2 + 1];
  const float* plane = logits + (size_t)b * OUTC * NPLANE;  // channel 0

  float x = __fsub_rn(__fmul_rn(px, 512.0f), 0.5f);
  float y = __fsub_rn(__fmul_rn(py, 512.0f), 0.5f);
  float x0f = floorf(x), y0f = floorf(y);
  float wx = __fsub_rn(x, x0f);
  float wy = __fsub_rn(y, y0f);
  int x0 = (int)x0f, y0 = (int)y0f;
  int x1 = x0 + 1, y1 = y0 + 1;
  bool vx0 = (x0 >= 0) & (x0 < HW);
  bool vx1 = (x1 >= 0) & (x1 < HW);
  bool vy0 = (y0 >= 0) & (y0 < HW);
  bool vy1 = (y1 >= 0) & (y1 < HW);
  float g00 = (vx0 && vy0) ? plane[y0 * HW + x0] : 0.0f;
  float g10 = (vx1 && vy0) ? plane[y0 * HW + x1] : 0.0f;
  float g01 = (vx0 && vy1) ? plane[y1 * HW + x0] : 0.0f;
  float g11 = (vx1 && vy1) ? plane[y1 * HW + x1] : 0.0f;
  float omx = __fsub_rn(1.0f, wx);
  float omy = __fsub_rn(1.0f, wy);
  float w00 = __fmul_rn(omx, omy);
  float w10 = __fmul_rn(wx, omy);
  float w01 = __fmul_rn(omx, wy);
  float w11 = __fmul_rn(wx, wy);
  float s = __fadd_rn(
      __fadd_rn(__fadd_rn(__fmul_rn(g00, w00), __fmul_rn(g10, w10)),
                __fmul_rn(g01, w01)),
      __fmul_rn(g11, w11));
  float e = xla_expf(-s);
  float sig = __fdiv_rn(1.0f, __fadd_rn(1.0f, e));
  float t = __fmul_rn(fabsf(__fsub_rn(sig, 0.5f)), 2.0f);
  u[gid] = __fsub_rn(1.0f, t);
}

// ---------------------------------------------------------------------------
// K2: exact stable top-k via ranking. Split-predicate refactor of the
// R2-verified kernel — EXACT counting identity, same float compares on the
// same values:
//   j <  wave_base       : (u_j>u_i)||(u_j==u_i && j<i)  ==  (u_j >= u_i)
//   j in [wb, wb+64)     : full original predicate (includes j==i -> 0)
//   j >= wave_base + 64  : ==  (u_j > u_i)
// 4 independent accumulators break the serial dependency chain (ILP at
// ~1 wave/SIMD occupancy).
// ---------------------------------------------------------------------------
__global__ __launch_bounds__(256) void k_select(const float* __restrict__ u,
                                                const float* __restrict__ rp,
                                                float* __restrict__ pts_out) {
  __shared__ __align__(16) float su[NS];
  int b = blockIdx.x / (NS / 256);
  int blk = blockIdx.x % (NS / 256);
  const float* ub = u + (size_t)b * NS;
  for (int t = threadIdx.x; t < NS / 4; t += 256)
    ((float4*)su)[t] = ((const float4*)ub)[t];
  __syncthreads();
  int i = blk * 256 + (int)threadIdx.x;
  int wb = i & ~63;  // wave-uniform (blk*256 is 64-aligned)
  float ui = su[i];
  int r0 = 0, r1 = 0, r2 = 0, r3 = 0;
  // Phase A: j < wb  ->  count (su[j] >= ui)
  for (int j = 0; j < wb; j += 8) {
    float4 v = *(const float4*)&su[j];
    float4 w = *(const float4*)&su[j + 4];
    r0 += (v.x >= ui) + (w.x >= ui);
    r1 += (v.y >= ui) + (w.y >= ui);
    r2 += (v.z >= ui) + (w.z >= ui);
    r3 += (v.w >= ui) + (w.w >= ui);
  }
  // Boundary chunk: full original predicate over 64 candidates
  for (int j = wb; j < wb + 64; ++j) {
    float vj = su[j];
    r0 += (vj > ui) || (vj == ui && j < i);
  }
  // Phase B: j >= wb+64  ->  count (su[j] > ui)
  for (int j = wb + 64; j < NS; j += 8) {
    float4 v = *(const float4*)&su[j];
    float4 w = *(const float4*)&su[j + 4];
    r0 += (v.x > ui) + (w.x > ui);
    r1 += (v.y > ui) + (w.y > ui);
    r2 += (v.z > ui) + (w.z > ui);
    r3 += (v.w > ui) + (w.w > ui);
  }
  int rank = (r0 + r1) + (r2 + r3);
  if (rank < NU) {
    pts_out[((size_t)b * NP + rank) * 2 + 0] = rp[((size_t)b * NS + i) * 2 + 0];
    pts_out[((size_t)b * NP + rank) * 2 + 1] = rp[((size_t)b * NS + i) * 2 + 1];
  }
}

// K2b: append the random-extra points (R2-verified).
__global__ void k_extra(const float* __restrict__ re, float* __restrict__ pts_out) {
  int gid = blockIdx.x * 256 + threadIdx.x;
  if (gid >= BATCH * NR) return;
  int b = gid / NR, j = gid % NR;
  pts_out[((size_t)b * NP + NU + j) * 2 + 0] = re[(size_t)gid * 2 + 0];
  pts_out[((size_t)b * NP + NU + j) * 2 + 1] = re[(size_t)gid * 2 + 1];
}

// ---------------------------------------------------------------------------
// K3a: per-point bilinear metadata: i00 (may be out-of-range; taps predicated
// by vmask bits, never loaded when invalid), 4 weights.
// ---------------------------------------------------------------------------
__global__ void k_prep(const float* __restrict__ pts, int2* __restrict__ m2,
                       float4* __restrict__ wts) {
  int g = blockIdx.x * 256 + threadIdx.x;
  if (g >= M_TOT) return;
  float px = pts[(size_t)g * 2 + 0];
  float py = pts[(size_t)g * 2 + 1];
  float x = px * 512.0f - 0.5f;
  float y = py * 512.0f - 0.5f;
  float x0f = floorf(x), y0f = floorf(y);
  float wx = x - x0f, wy = y - y0f;
  int x0 = (int)x0f, y0 = (int)y0f;
  bool vx0 = (unsigned)x0 < (unsigned)HW;
  bool vx1 = (unsigned)(x0 + 1) < (unsigned)HW;
  bool vy0 = (unsigned)y0 < (unsigned)HW;
  bool vy1 = (unsigned)(y0 + 1) < (unsigned)HW;
  int vm = (int)(vx0 && vy0) | ((int)(vx1 && vy0) << 1) |
           ((int)(vx0 && vy1) << 2) | ((int)(vx1 && vy1) << 3);
  m2[g] = make_int2(y0 * HW + x0, vm);
  wts[g] = make_float4((1.0f - wx) * (1.0f - wy), wx * (1.0f - wy),
                       (1.0f - wx) * wy, wx * wy);
}

// ---------------------------------------------------------------------------
// K3b: gather, natural point order, one block per (channel, batch, quarter).
// GCH_SPLIT=4: 3072 blocks -> full occupancy; 4 points/thread fully unrolled
// for deep vmcnt pipelining. Output transposed: featsT[c][b*NP + s].
// ---------------------------------------------------------------------------
__global__ __launch_bounds__(256) void k_gather3(
    const float* __restrict__ fine, const float* __restrict__ coarse,
    const int2* __restrict__ m2, const float4* __restrict__ wts,
    float* __restrict__ featsT) {
  int c = blockIdx.x % CIN;
  int rem = blockIdx.x / CIN;
  int b = rem & (BATCH - 1);
  int part = rem >> 2;
  const float* plane = (c < CF_CH)
                           ? fine + ((size_t)b * CF_CH + c) * NPLANE
                           : coarse + ((size_t)b * CC_CH + (c - CF_CH)) * NPLANE;
  const int2* m2b = m2 + (size_t)b * NP;
  const float4* wtsb = wts + (size_t)b * NP;
  float* outrow = featsT + (size_t)c * M_TOT + (size_t)b * NP;
  int s0 = part * (NP / GCH_SPLIT);
#pragma unroll
  for (int q = 0; q < NP / GCH_SPLIT / 256; ++q) {
    int s = s0 + q * 256 + (int)threadIdx.x;
    int2 mm = m2b[s];
    float4 w = wtsb[s];
    const float* bp = plane + mm.x;
    float t00 = 0.0f, t10 = 0.0f, t01 = 0.0f, t11 = 0.0f;
    if (mm.y & 1) t00 = bp[0] * w.x;
    if (mm.y & 2) t10 = bp[1] * w.y;
    if (mm.y & 4) t01 = bp[HW] * w.z;
    if (mm.y & 8) t11 = bp[HW + 1] * w.w;
    outrow[s] = ((t00 + t10) + t01) + t11;
  }
}

// ---------------------------------------------------------------------------
// K4: GEMM layer 1 from transposed A (At[k][m]), C[M][256] row-major.
// 64x64 tile, BK=32, 256 threads, 4x4 acc.
// ---------------------------------------------------------------------------
__global__ __launch_bounds__(256) void k_gemm1_At(const float* __restrict__ At,
                                                  const float* __restrict__ W,
                                                  const float* __restrict__ bias,
                                                  float* __restrict__ C) {
  __shared__ __align__(16) float As[32][68];
  __shared__ __align__(16) float Bs[32][68];
  const int bx = blockIdx.x & 3;   // N tile
  const int by = blockIdx.x >> 2;  // M tile
  const int tid = threadIdx.x;
  const int tn = tid & 15, tm = tid >> 4;
  const int m_base = by * 64, n_base = bx * 64;
  float acc[4][4] = {};
  for (int k0 = 0; k0 < CIN; k0 += 32) {
#pragma unroll
    for (int r = 0; r < 2; ++r) {
      int t = tid + r * 256;
      int kk = t >> 4, mg = (t & 15) * 4;
      *(float4*)&As[kk][mg] =
          *(const float4*)&At[(size_t)(k0 + kk) * M_TOT + m_base + mg];
      int row = t >> 3, cg = (t & 7) * 4;
      float4 vw = *(const float4*)&W[(size_t)(n_base + row) * CIN + k0 + cg];
      Bs[cg + 0][row] = vw.x;
      Bs[cg + 1][row] = vw.y;
      Bs[cg + 2][row] = vw.z;
      Bs[cg + 3][row] = vw.w;
    }
    __syncthreads();
#pragma unroll
    for (int kk = 0; kk < 32; ++kk) {
      float4 a4 = *(const float4*)&As[kk][tm * 4];
      float4 b4 = *(const float4*)&Bs[kk][tn * 4];
      float av[4] = {a4.x, a4.y, a4.z, a4.w};
      float bw[4] = {b4.x, b4.y, b4.z, b4.w};
#pragma unroll
      for (int i = 0; i < 4; ++i)
#pragma unroll
        for (int j = 0; j < 4; ++j) acc[i][j] = fmaf(av[i], bw[j], acc[i][j]);
    }
    __syncthreads();
  }
  float bs[4];
#pragma unroll
  for (int j = 0; j < 4; ++j) bs[j] = bias[n_base + tn * 4 + j];
#pragma unroll
  for (int i = 0; i < 4; ++i) {
    float4 o;
    o.x = fmaxf(acc[i][0] + bs[0], 0.0f);
    o.y = fmaxf(acc[i][1] + bs[1], 0.0f);
    o.z = fmaxf(acc[i][2] + bs[2], 0.0f);
    o.w = fmaxf(acc[i][3] + bs[3], 0.0f);
    *(float4*)&C[(size_t)(m_base + tm * 4 + i) * HID + n_base + tn * 4] = o;
  }
}

// ---------------------------------------------------------------------------
// K5: GEMM layer 2 (row-major A).
// ---------------------------------------------------------------------------
template <int K>
__global__ __launch_bounds__(256) void k_gemm_relu(const float* __restrict__ A,
                                                   const float* __restrict__ W,
                                                   const float* __restrict__ bias,
                                                   float* __restrict__ C) {
  __shared__ __align__(16) float As[32][68];
  __shared__ __align__(16) float Bs[32][68];
  const int bx = blockIdx.x & 3;
  const int by = blockIdx.x >> 2;
  const int tid = threadIdx.x;
  const int tn = tid & 15, tm = tid >> 4;
  const int m_base = by * 64, n_base = bx * 64;
  float acc[4][4] = {};
  for (int k0 = 0; k0 < K; k0 += 32) {
#pragma unroll
    for (int r = 0; r < 2; ++r) {
      int t = tid + r * 256;
      int row = t >> 3, cg = (t & 7) * 4;
      float4 va = *(const float4*)&A[(size_t)(m_base + row) * K + k0 + cg];
      As[cg + 0][row] = va.x;
      As[cg + 1][row] = va.y;
      As[cg + 2][row] = va.z;
      As[cg + 3][row] = va.w;
      float4 vw = *(const float4*)&W[(size_t)(n_base + row) * K + k0 + cg];
      Bs[cg + 0][row] = vw.x;
      Bs[cg + 1][row] = vw.y;
      Bs[cg + 2][row] = vw.z;
      Bs[cg + 3][row] = vw.w;
    }
    __syncthreads();
#pragma unroll
    for (int kk = 0; kk < 32; ++kk) {
      float4 a4 = *(const float4*)&As[kk][tm * 4];
      float4 b4 = *(const float4*)&Bs[kk][tn * 4];
      float av[4] = {a4.x, a4.y, a4.z, a4.w};
      float bw[4] = {b4.x, b4.y, b4.z, b4.w};
#pragma unroll
      for (int i = 0; i < 4; ++i)
#pragma unroll
        for (int j = 0; j < 4; ++j) acc[i][j] = fmaf(av[i], bw[j], acc[i][j]);
    }
    __syncthreads();
  }
  float bs[4];
#pragma unroll
  for (int j = 0; j < 4; ++j) bs[j] = bias[n_base + tn * 4 + j];
#pragma unroll
  for (int i = 0; i < 4; ++i) {
    float4 o;
    o.x = fmaxf(acc[i][0] + bs[0], 0.0f);
    o.y = fmaxf(acc[i][1] + bs[1], 0.0f);
    o.z = fmaxf(acc[i][2] + bs[2], 0.0f);
    o.w = fmaxf(acc[i][3] + bs[3], 0.0f);
    *(float4*)&C[(size_t)(m_base + tm * 4 + i) * HID + n_base + tn * 4] = o;
  }
}

// ---------------------------------------------------------------------------
// K6: final layer, 4 outputs per point, shuffle reduce.
// ---------------------------------------------------------------------------
__global__ __launch_bounds__(256) void k_out(const float* __restrict__ h,
                                             const float* __restrict__ W3,
                                             const float* __restrict__ b3,
                                             float* __restrict__ out) {
  int gp = blockIdx.x * 4 + (threadIdx.x >> 6);
  int lane = threadIdx.x & 63;
  const float* hr = h + (size_t)gp * HID;
  float4 hv = *(const float4*)&hr[lane * 4];
  float s[4];
#pragma unroll
  for (int o = 0; o < 4; ++o) {
    float4 w = *(const float4*)&W3[o * HID + lane * 4];
    s[o] = hv.x * w.x + hv.y * w.y + hv.z * w.z + hv.w * w.w;
  }
#pragma unroll
  for (int off = 32; off; off >>= 1)
#pragma unroll
    for (int o = 0; o < 4; ++o) s[o] += __shfl_xor(s[o], off, 64);
  if (lane == 0) {
    int b = gp / NP, n = gp % NP;
#pragma unroll
    for (int o = 0; o < 4; ++o)
      out[((size_t)b * OUTC + o) * NP + n] = s[o] + b3[o];
  }
}

extern "C" void kernel_launch(void* const* d_in, const int* in_sizes, int n_in,
                              void* d_out, int out_size, void* d_ws, size_t ws_size,
                              hipStream_t stream) {
  const float* fine = (const float*)d_in[0];
  const float* coarse = (const float*)d_in[1];
  const float* logits = (const float*)d_in[2];
  const float* rand_points = (const float*)d_in[3];
  const float* rand_extra = (const float*)d_in[4];
  const float* W1 = (const float*)d_in[5];
  const float* b1 = (const float*)d_in[6];
  const float* W2 = (const float*)d_in[7];
  const float* b2 = (const float*)d_in[8];
  const float* W3 = (const float*)d_in[9];
  const float* b3 = (const float*)d_in[10];
  float* out = (float*)d_out;

  float* out_logits = out;
  float* out_points = out + (size_t)BATCH * OUTC * NP;

  // ws layout (bytes): u | m2 | wts | featsT | h1 | h2
  char* ws = (char*)d_ws;
  float* u = (float*)(ws + 0);              // 196608
  int2* m2 = (int2*)(ws + 196608);          // 131072
  float4* wts = (float4*)(ws + 327680);     // 262144
  float* featsT = (float*)(ws + 589824);    // 12582912
  float* h1 = (float*)(ws + 13172736);      // 16777216
  float* h2 = (float*)(ws + 29949952);      // 16777216

  k_uncert<<<(BATCH * NS + 255) / 256, 256, 0, stream>>>(logits, rand_points, u);
  k_select<<<BATCH * (NS / 256), 256, 0, stream>>>(u, rand_points, out_points);
  k_extra<<<(BATCH * NR + 255) / 256, 256, 0, stream>>>(rand_extra, out_points);
  k_prep<<<(M_TOT + 255) / 256, 256, 0, stream>>>(out_points, m2, wts);
  k_gather3<<<CIN * BATCH * GCH_SPLIT, 256, 0, stream>>>(fine, coarse, m2, wts,
                                                         featsT);
  k_gemm1_At<<<(M_TOT / 64) * 4, 256, 0, stream>>>(featsT, W1, b1, h1);
  k_gemm_relu<HID><<<(M_TOT / 64) * 4, 256, 0, stream>>>(h1, W2, b2, h2);
  k_out<<<M_TOT / 4, 256, 0, stream>>>(h2, W3, b3, out_logits);
}